// Round 17
// baseline (502.356 us; speedup 1.0000x reference)
//
#include <hip/hip_runtime.h>
#include <hip/hip_bf16.h>

// Problem constants
#define BB   256
#define LL   168
#define CC   36
#define FF   64
#define SSTEP 56   // L / 3

typedef __attribute__((ext_vector_type(8))) _Float16 half8;
typedef __attribute__((ext_vector_type(4))) _Float16 half4;
typedef __attribute__((ext_vector_type(4))) float f32x4;
typedef __attribute__((ext_vector_type(4))) int i32x4;

#define MFMA16(a,b,c) __builtin_amdgcn_mfma_f32_16x16x32_f16(a,b,c,0,0,0)

// ---------------- K0: one-time weight prep (f16, per-lane-linear MFMA layouts) ----------------
// wcb: [3 layer][2 kk][5 t][4 mt][64 lane][8 j] f16 — fo=mt*16+(lane&15), fi=kk*32+(lane>>4)*8+j
// pwb: [4 p][6 kkp][4 w][64 lane][8 j] f16 — q=w*16+(lane&15), k' = kkp*32+(lane>>4)*8+j,
//      with d-major k-order: k' = d*64 + f  (original k = f*3 + d)
// fcB: [256 d][2304 kc] f16, kc = c*64+q, value = fcw[d][q*36+c]
__global__ __launch_bounds__(256) void k0_prep(
    const float* __restrict__ w1, const float* __restrict__ w2, const float* __restrict__ w3,
    const float* __restrict__ wq, const float* __restrict__ wk,
    const float* __restrict__ wv, const float* __restrict__ wv1,
    const float* __restrict__ fcw,
    _Float16* __restrict__ wcb, _Float16* __restrict__ pwb, _Float16* __restrict__ fcB)
{
    const int N1 = 61440;
    const int N2 = 49152;
    const int N3 = 589824;
    int idx = blockIdx.x * 256 + threadIdx.x;
    if (idx < N1) {
        int lin = idx;
        int j    = lin & 7;   lin >>= 3;
        int lane = lin & 63;  lin >>= 6;
        int mt   = lin & 3;   lin >>= 2;
        int t    = lin % 5;   lin /= 5;
        int kk   = lin & 1;
        int layer = lin >> 1;
        int fo = mt * 16 + (lane & 15);
        int fi = kk * 32 + (lane >> 4) * 8 + j;
        const float* w = (layer == 0) ? w1 : (layer == 1) ? w2 : w3;
        wcb[idx] = (_Float16)w[fo * 320 + fi * 5 + t];
    } else if (idx < N1 + N2) {
        int e = idx - N1;
        int p = e / 12288, r = e % 12288;
        int kkp = r / 2048, r2 = r % 2048;
        int wv_ = r2 / 512, r3 = r2 % 512;
        int lane = r3 / 8, j = r3 % 8;
        int q  = wv_ * 16 + (lane & 15);
        int kp = kkp * 32 + (lane >> 4) * 8 + j;   // d-major k'
        int d  = kp >> 6, f = kp & 63;
        const float* w = (p == 0) ? wq : (p == 1) ? wk : (p == 2) ? wv : wv1;
        pwb[e] = (_Float16)w[q * 192 + f * 3 + d];
    } else if (idx < N1 + N2 + N3) {
        int e = idx - N1 - N2;
        int d = e / 2304, kc = e % 2304;
        int cc = kc >> 6, q = kc & 63;
        fcB[e] = (_Float16)fcw[d * 2304 + q * 36 + cc];
    }
}

// ---------------- K1: fused MFMA conv stack + projections, one (b,c) per 512-thread block ----
// 8 wave-roles: conv wave wi owns 4mt x 2nt (nt = wi + 8i) -> acc 32 VGPR (live ~70).
// launch_bounds(512,6): VGPR cap ~85, 3 blocks/CU by LDS (30.9KB) -> 24 waves/CU target.
// A-operands: per-t batched register loads (L1-hot). O/P staged in obuf, nontemporal out.
__global__ __launch_bounds__(512, 6) void k1_conv_proj(
    const float* __restrict__ x,
    const float* __restrict__ w0, const float* __restrict__ cb0,
    const float* __restrict__ cb1, const float* __restrict__ cb2,
    const float* __restrict__ cb3,
    const _Float16* __restrict__ wcb,
    const _Float16* __restrict__ pwb,
    const float* __restrict__ gamma,
    _Float16* __restrict__ P,   // chunk-local [bl*56+s][4 p][2304 = c*64+q]
    _Float16* __restrict__ O,   // GLOBAL [b*56+s][2304 = c*64+q]
    int b_start)
{
    __shared__ int4 hbv[1440];     // 23040 B: 180 rows x 128B
    __shared__ int4 obv[448];      //  7168 B: O/P staging [56 s][128B of q]
    __shared__ float xl[176];
    char* hb = (char*)hbv;
    char* ob = (char*)obv;
    const int tid  = threadIdx.x;
    const int lane = tid & 63, wi = tid >> 6;   // wi = wave role 0..7
    const int c = blockIdx.x % CC, bl = blockIdx.x / CC, b = b_start + bl;
    const float gam = gamma[0];
    const int4 IZ = make_int4(0, 0, 0, 0);
    const f32x4 FZ = {0.f, 0.f, 0.f, 0.f};
    const int pfirst = (gam == 0.f) ? 3 : 0;

    // zero ONLY pad rows of hb (rows 0,1 and 170..179); conv0 fills rows 2..169
    if (tid < 16) hbv[tid] = IZ;                       // rows 0,1
    if (tid >= 32 && tid < 112) hbv[1328 + tid] = IZ;  // rows 170..179
    if (tid < 176) {
        int l = tid - 2;
        xl[tid] = (l >= 0 && l < LL) ? x[((size_t)b * LL + l) * CC + c] : 0.f;
    }
    __syncthreads();   // xl + pad-zero visible

    // ---- conv0: fo = lane, l segment = wi*21 .. +21 (rolling window) ----
    {
        float wt0 = w0[lane*5], wt1 = w0[lane*5+1], wt2 = w0[lane*5+2],
              wt3 = w0[lane*5+3], wt4 = w0[lane*5+4];
        float bb = cb0[lane];
        const int l0 = wi * 21;
        float h0 = xl[l0], h1 = xl[l0+1], h2 = xl[l0+2], h3 = xl[l0+3];
        #pragma unroll 7
        for (int i = 0; i < 21; ++i) {
            float h4 = xl[l0 + i + 4];
            float a = bb + wt0*h0 + wt1*h1 + wt2*h2 + wt3*h3 + wt4*h4;
            int row = l0 + i + 2;
            *(_Float16*)(hb + row*128 + ((lane*2) ^ ((row&7)<<4))) = (_Float16)fmaxf(a, 0.f);
            h0 = h1; h1 = h2; h2 = h3; h3 = h4;
        }
    }
    __syncthreads();   // conv0 h visible

    const int fo = lane & 15;
    const int g8 = (lane >> 4) << 4;

    // ---- conv1..3 via MFMA: wave wi computes 4 mt x nt in {wi, wi+8} (guard nt<11) ----
    #pragma unroll 1
    for (int layer = 0; layer < 3; ++layer) {
        const float* bias = (layer == 0) ? cb1 : (layer == 1) ? cb2 : cb3;
        f32x4 acc[4][2];
        #pragma unroll
        for (int mt = 0; mt < 4; ++mt)
            #pragma unroll
            for (int i = 0; i < 2; ++i) acc[mt][i] = FZ;

        #pragma unroll
        for (int kk = 0; kk < 2; ++kk) {
            const _Float16* wb = wcb + layer*20480 + kk*10240 + lane*8;
            const int cb = kk*64 + g8;
            #pragma unroll
            for (int t = 0; t < 5; ++t) {
                // per-t A batch: 4 coalesced dwordx4 from L1-hot weights (16 VGPR live)
                half8 a0 = *(const half8*)(wb + t*2048 + 0*512);
                half8 a1 = *(const half8*)(wb + t*2048 + 1*512);
                half8 a2 = *(const half8*)(wb + t*2048 + 2*512);
                half8 a3 = *(const half8*)(wb + t*2048 + 3*512);
                #pragma unroll
                for (int i = 0; i < 2; ++i) {
                    const int nt = wi + 8*i;
                    if (nt < 11) {
                        int row = nt*16 + fo + t;
                        half8 bf = *(const half8*)(hb + row*128 + (cb ^ ((row&7)<<4)));
                        acc[0][i] = MFMA16(a0, bf, acc[0][i]);
                        acc[1][i] = MFMA16(a1, bf, acc[1][i]);
                        acc[2][i] = MFMA16(a2, bf, acc[2][i]);
                        acc[3][i] = MFMA16(a3, bf, acc[3][i]);
                    }
                }
            }
        }
        __syncthreads();   // all hb reads complete before in-place write

        // epilogue: bias + relu; layers 0,1 -> h in place; layer 2 -> pk repack (d-major k')
        if (layer < 2) {
            #pragma unroll
            for (int mt = 0; mt < 4; ++mt) {
                const int fo0 = mt*16 + ((lane>>4)<<2);
                const float bb0 = bias[fo0], bb1 = bias[fo0+1],
                            bb2 = bias[fo0+2], bb3 = bias[fo0+3];
                #pragma unroll
                for (int i = 0; i < 2; ++i) {
                    const int nt = wi + 8*i;
                    const int l  = nt*16 + fo;
                    if (nt < 11 && l < LL) {
                        int row = l + 2;
                        half4 hv;
                        hv.x = (_Float16)fmaxf(acc[mt][i].x + bb0, 0.f);
                        hv.y = (_Float16)fmaxf(acc[mt][i].y + bb1, 0.f);
                        hv.z = (_Float16)fmaxf(acc[mt][i].z + bb2, 0.f);
                        hv.w = (_Float16)fmaxf(acc[mt][i].w + bb3, 0.f);
                        *(half4*)(hb + row*128 + ((fo0*2) ^ ((row&7)<<4))) = hv;
                    }
                }
            }
        } else {
            #pragma unroll
            for (int mt = 0; mt < 4; ++mt) {
                const int fo0 = mt*16 + ((lane>>4)<<2);
                const float bb0 = bias[fo0], bb1 = bias[fo0+1],
                            bb2 = bias[fo0+2], bb3 = bias[fo0+3];
                #pragma unroll
                for (int i = 0; i < 2; ++i) {
                    const int nt = wi + 8*i;
                    const int l  = nt*16 + fo;
                    if (nt < 11 && l < LL) {
                        const int s = l / 3, d = l - s*3;
                        const int ssw = (s & 7) << 4;
                        half4 hv;
                        hv.x = (_Float16)fmaxf(acc[mt][i].x + bb0, 0.f);
                        hv.y = (_Float16)fmaxf(acc[mt][i].y + bb1, 0.f);
                        hv.z = (_Float16)fmaxf(acc[mt][i].z + bb2, 0.f);
                        hv.w = (_Float16)fmaxf(acc[mt][i].w + bb3, 0.f);
                        // k' = d*64 + f: one contiguous half4 at f=fo0..fo0+3
                        *(half4*)(hb + s*384 + ((d*128 + fo0*2) ^ ssw)) = hv;
                    }
                }
            }
        }
        __syncthreads();   // writes visible
    }

    // ---- projections: 8 waves = 4 q-strips x 2 s-halves; A in regs, B = pk in hb ----
    const half8 HZ = {(_Float16)0,(_Float16)0,(_Float16)0,(_Float16)0,
                      (_Float16)0,(_Float16)0,(_Float16)0,(_Float16)0};
    const int qs = wi & 3;       // q strip
    const int sh = wi >> 2;      // s half: s = sh*32 + nt*16 + fo, nt<2
    #pragma unroll 1
    for (int p = pfirst; p < 4; ++p) {
        f32x4 pacc[2] = {FZ, FZ};
        const _Float16* ab = pwb + p*12288 + qs*512 + lane*8;
        #pragma unroll
        for (int kkp = 0; kkp < 6; ++kkp) {
            half8 af = *(const half8*)(ab + kkp*2048);
            const int cb = kkp*64 + g8;
            #pragma unroll
            for (int nt = 0; nt < 2; ++nt) {
                const int s = sh*32 + nt*16 + fo;
                half8 bf = HZ;
                if (s < SSTEP)
                    bf = *(const half8*)(hb + s*384 + (cb ^ ((s&7)<<4)));
                pacc[nt] = MFMA16(af, bf, pacc[nt]);
            }
        }
        // stage this p-slice into obuf [s][q] (swizzled rows)
        __syncthreads();   // prior flush reads of obuf complete
        const int q0 = qs*16 + ((lane>>4)<<2);
        const bool relu = (p == 3 && gam == 0.f);
        #pragma unroll
        for (int nt = 0; nt < 2; ++nt) {
            const int s = sh*32 + nt*16 + fo;
            if (s >= SSTEP) continue;
            half4 o;
            if (relu) {
                o.x = (_Float16)fmaxf(pacc[nt].x, 0.f);
                o.y = (_Float16)fmaxf(pacc[nt].y, 0.f);
                o.z = (_Float16)fmaxf(pacc[nt].z, 0.f);
                o.w = (_Float16)fmaxf(pacc[nt].w, 0.f);
            } else {
                o.x = (_Float16)pacc[nt].x;
                o.y = (_Float16)pacc[nt].y;
                o.z = (_Float16)pacc[nt].z;
                o.w = (_Float16)pacc[nt].w;
            }
            *(half4*)(ob + s*128 + ((q0*2) ^ ((s&7)<<4))) = o;
        }
        __syncthreads();   // obuf complete
        // coalesced nontemporal write: 56 rows x 128B full segments
        if (tid < 448) {
            int s = tid >> 3, j = tid & 7;
            i32x4 v = *(const i32x4*)(ob + s*128 + ((j*16) ^ ((s&7)<<4)));
            _Float16* dst;
            if (relu) {
                const size_t bsO = (size_t)b * SSTEP + s;
                dst = O + bsO*2304 + c*64 + j*8;
            } else {
                const size_t bsP = (size_t)bl * SSTEP + s;
                dst = P + (bsP*4 + p)*2304 + c*64 + j*8;
            }
            __builtin_nontemporal_store(v, (i32x4*)dst);
        }
    }
}

// ---------------- K2: attention (general gamma path only) ----------------
__global__ __launch_bounds__(256) void k2_attn(
    const _Float16* __restrict__ P,
    const float* __restrict__ gamma,
    _Float16* __restrict__ O)      // chunk-offset pointer
{
    const float gam = gamma[0];
    if (gam == 0.f) return;
    const int bs  = blockIdx.x;
    const int tid = threadIdx.x;
    __shared__ float pb[4][CC][FF];
    __shared__ float sc[CC][CC];

    const size_t base = (size_t)bs * 4 * 2304;
    for (int idx = tid; idx < 4 * 2304; idx += 256)
        ((float*)pb)[idx] = (float)P[base + idx];
    __syncthreads();

    for (int idx = tid; idx < CC * CC; idx += 256) {
        int i = idx / CC, jj = idx % CC;
        float a = 0.f;
        for (int qq = 0; qq < FF; ++qq) a += pb[0][i][qq] * pb[1][jj][qq];
        sc[i][jj] = a;
    }
    __syncthreads();
    if (tid < CC) {
        int jj = tid;
        float m = -1e30f;
        for (int i = 0; i < CC; ++i) m = fmaxf(m, sc[i][jj]);
        float ssum = 0.f;
        for (int i = 0; i < CC; ++i) ssum += expf(sc[i][jj] - m);
        float inv = 1.f / ssum;
        for (int i = 0; i < CC; ++i) sc[i][jj] = expf(sc[i][jj] - m) * inv;
    }
    __syncthreads();

    for (int idx = tid; idx < FF * CC; idx += 256) {
        int qq = idx / CC, jj = idx % CC;
        float a = 0.f;
        for (int i = 0; i < CC; ++i) a += pb[2][i][qq] * sc[i][jj];
        float o = gam * a + pb[3][jj][qq];
        O[(size_t)bs * 2304 + jj * 64 + qq] = (_Float16)fmaxf(o, 0.f);
    }
}

// ---------------- K3: FC via MFMA, BK=64 (8 MFMA per barrier-pair), single launch ----------------
__global__ __launch_bounds__(256) void k3_fc(
    const _Float16* __restrict__ O,     // [rows][2304]
    const _Float16* __restrict__ fcB,   // [256][2304]
    const float* __restrict__ fcb,
    float* __restrict__ out,            // [rows][256]
    int rows, int gm)
{
    const int bm = blockIdx.x % gm, bn = blockIdx.x / gm;
    const int r0 = bm * 64, c0 = bn * 64;
    const int tid = threadIdx.x, lane = tid & 63, wid = tid >> 6;
    __shared__ _Float16 As[64][72];   // 144B stride (16B aligned, ~2-way banks)
    __shared__ _Float16 Bs[64][72];

    const f32x4 FZ = {0.f, 0.f, 0.f, 0.f};
    f32x4 acc[4] = {FZ, FZ, FZ, FZ};
    const int rr = tid >> 2, k8 = (tid & 3) * 8;   // 4 threads per row, 2x int4 each
    const int4 IZ = make_int4(0, 0, 0, 0);
    const int fo = lane & 15, g = lane >> 4;

    for (int k0 = 0; k0 < 2304; k0 += 64) {
        __syncthreads();
        {
            const bool rok = (r0 + rr < rows);
            int4 a0 = rok ? *(const int4*)(O + (size_t)(r0 + rr) * 2304 + k0 + k8) : IZ;
            int4 a1 = rok ? *(const int4*)(O + (size_t)(r0 + rr) * 2304 + k0 + 32 + k8) : IZ;
            *(int4*)&As[rr][k8]      = a0;
            *(int4*)&As[rr][k8 + 32] = a1;
            *(int4*)&Bs[rr][k8]      = *(const int4*)(fcB + (size_t)(c0 + rr) * 2304 + k0 + k8);
            *(int4*)&Bs[rr][k8 + 32] = *(const int4*)(fcB + (size_t)(c0 + rr) * 2304 + k0 + 32 + k8);
        }
        __syncthreads();
        #pragma unroll
        for (int kk2 = 0; kk2 < 2; ++kk2) {
            const int ko = kk2*32 + g*8;
            half8 af = *(const half8*)&As[wid*16 + fo][ko];
            #pragma unroll
            for (int ct = 0; ct < 4; ++ct) {
                half8 bf = *(const half8*)&Bs[ct*16 + fo][ko];
                acc[ct] = MFMA16(af, bf, acc[ct]);
            }
        }
    }
    #pragma unroll
    for (int ct = 0; ct < 4; ++ct) {
        const int d = c0 + ct*16 + fo;
        const float bb = fcb[d];
        #pragma unroll
        for (int r = 0; r < 4; ++r) {
            const int row = r0 + wid*16 + g*4 + r;
            if (row < rows) out[(size_t)row * 256 + d] = fmaxf(acc[ct][r] + bb, 0.f);
        }
    }
}

extern "C" void kernel_launch(void* const* d_in, const int* in_sizes, int n_in,
                              void* d_out, int out_size, void* d_ws, size_t ws_size,
                              hipStream_t stream)
{
    const float* x     = (const float*)d_in[0];
    const float* w0    = (const float*)d_in[1];
    const float* b0    = (const float*)d_in[2];
    const float* w1    = (const float*)d_in[3];
    const float* b1    = (const float*)d_in[4];
    const float* w2    = (const float*)d_in[5];
    const float* b2    = (const float*)d_in[6];
    const float* w3    = (const float*)d_in[7];
    const float* b3    = (const float*)d_in[8];
    const float* wq    = (const float*)d_in[9];
    const float* wk    = (const float*)d_in[10];
    const float* wv    = (const float*)d_in[11];
    const float* wv1   = (const float*)d_in[12];
    const float* gamma = (const float*)d_in[13];
    const float* fcw   = (const float*)d_in[14];
    const float* fcb   = (const float*)d_in[15];
    float* out = (float*)d_out;

    // ws: weights (1.4MB) | O full [256*56][2304] f16 (66MB) | P chunk [Bc*56][4][2304] f16
    const size_t fixedB  = (size_t)(61440 + 49152 + 589824) * 2;          // 1,400,832
    const size_t O_FULL  = (size_t)BB * SSTEP * 2304 * 2;                 // 66,060,288
    const size_t perB_P  = (size_t)SSTEP * 4 * 2304 * 2;                  // 1,032,192
    int Bc = 256;
    while (Bc > 1 && fixedB + O_FULL + (size_t)Bc * perB_P > ws_size) Bc >>= 1;

    char* ws = (char*)d_ws;
    _Float16* wcb = (_Float16*)ws;
    _Float16* pwb = wcb + 61440;
    _Float16* fcB = pwb + 49152;
    _Float16* O   = (_Float16*)(ws + fixedB);
    _Float16* P   = O + (size_t)BB * SSTEP * 2304;

    const int prep_total = 61440 + 49152 + 589824;
    k0_prep<<<(prep_total + 255) / 256, 256, 0, stream>>>(w1, w2, w3, wq, wk, wv, wv1,
                                                          fcw, wcb, pwb, fcB);

    for (int bst = 0; bst < BB; bst += Bc) {
        int bcur = (bst + Bc <= BB) ? Bc : (BB - bst);
        k1_conv_proj<<<bcur * CC, 512, 0, stream>>>(x, w0, b0, b1, b2, b3,
                                                    wcb, pwb, gamma, P, O, bst);
        k2_attn<<<bcur * SSTEP, 256, 0, stream>>>(P, gamma,
                                                  O + (size_t)bst * SSTEP * 2304);
    }
    k3_fc<<<224 * 4, 256, 0, stream>>>(O, fcB, fcb, out, BB * SSTEP, 224);
}

// Round 18
// 312.992 us; speedup vs baseline: 1.6050x; 1.6050x over previous
//
#include <hip/hip_runtime.h>
#include <hip/hip_bf16.h>

// Problem constants
#define BB   256
#define LL   168
#define CC   36
#define FF   64
#define SSTEP 56   // L / 3

typedef __attribute__((ext_vector_type(8))) _Float16 half8;
typedef __attribute__((ext_vector_type(4))) _Float16 half4;
typedef __attribute__((ext_vector_type(4))) float f32x4;
typedef __attribute__((ext_vector_type(4))) int i32x4;

#define MFMA16(a,b,c) __builtin_amdgcn_mfma_f32_16x16x32_f16(a,b,c,0,0,0)

// ---------------- K0: one-time weight prep (f16, per-lane-linear MFMA layouts) ----------------
// wcb: [3 layer][2 kk][5 t][4 mt][64 lane][8 j] f16 — fo=mt*16+(lane&15), fi=kk*32+(lane>>4)*8+j
// pwb: [4 p][6 kkp][4 w][64 lane][8 j] f16 — q=w*16+(lane&15), k' = kkp*32+(lane>>4)*8+j,
//      with d-major k-order: k' = d*64 + f  (original k = f*3 + d)
// fcB: [256 d][2304 kc] f16, kc = c*64+q, value = fcw[d][q*36+c]
__global__ __launch_bounds__(256) void k0_prep(
    const float* __restrict__ w1, const float* __restrict__ w2, const float* __restrict__ w3,
    const float* __restrict__ wq, const float* __restrict__ wk,
    const float* __restrict__ wv, const float* __restrict__ wv1,
    const float* __restrict__ fcw,
    _Float16* __restrict__ wcb, _Float16* __restrict__ pwb, _Float16* __restrict__ fcB)
{
    const int N1 = 61440;
    const int N2 = 49152;
    const int N3 = 589824;
    int idx = blockIdx.x * 256 + threadIdx.x;
    if (idx < N1) {
        int lin = idx;
        int j    = lin & 7;   lin >>= 3;
        int lane = lin & 63;  lin >>= 6;
        int mt   = lin & 3;   lin >>= 2;
        int t    = lin % 5;   lin /= 5;
        int kk   = lin & 1;
        int layer = lin >> 1;
        int fo = mt * 16 + (lane & 15);
        int fi = kk * 32 + (lane >> 4) * 8 + j;
        const float* w = (layer == 0) ? w1 : (layer == 1) ? w2 : w3;
        wcb[idx] = (_Float16)w[fo * 320 + fi * 5 + t];
    } else if (idx < N1 + N2) {
        int e = idx - N1;
        int p = e / 12288, r = e % 12288;
        int kkp = r / 2048, r2 = r % 2048;
        int wv_ = r2 / 512, r3 = r2 % 512;
        int lane = r3 / 8, j = r3 % 8;
        int q  = wv_ * 16 + (lane & 15);
        int kp = kkp * 32 + (lane >> 4) * 8 + j;   // d-major k'
        int d  = kp >> 6, f = kp & 63;
        const float* w = (p == 0) ? wq : (p == 1) ? wk : (p == 2) ? wv : wv1;
        pwb[e] = (_Float16)w[q * 192 + f * 3 + d];
    } else if (idx < N1 + N2 + N3) {
        int e = idx - N1 - N2;
        int d = e / 2304, kc = e % 2304;
        int cc = kc >> 6, q = kc & 63;
        fcB[e] = (_Float16)fcw[d * 2304 + q * 36 + cc];
    }
}

// ---------------- K1: fused MFMA conv stack + projections, one (b,c) per block ----------------
// r15 structure (best measured, no spills): 256 threads, launch_bounds(256,4).
// LDS: hb 23040B + obuf 7168B + xl. A-operands: per-t batched register loads (L1-hot).
// O/P written as full 128B row segments, nontemporal. O is GLOBAL (single k3 later).
__global__ __launch_bounds__(256, 4) void k1_conv_proj(
    const float* __restrict__ x,
    const float* __restrict__ w0, const float* __restrict__ cb0,
    const float* __restrict__ cb1, const float* __restrict__ cb2,
    const float* __restrict__ cb3,
    const _Float16* __restrict__ wcb,
    const _Float16* __restrict__ pwb,
    const float* __restrict__ gamma,
    _Float16* __restrict__ P,   // chunk-local [bl*56+s][4 p][2304 = c*64+q]
    _Float16* __restrict__ O,   // GLOBAL [b*56+s][2304 = c*64+q]
    int b_start)
{
    __shared__ int4 hbv[1440];     // 23040 B
    __shared__ int4 obv[448];      //  7168 B: O/P staging, [56 s][128B of q]
    __shared__ float xl[176];
    char* hb  = (char*)hbv;
    char* ob  = (char*)obv;
    const int tid  = threadIdx.x;
    const int lane = tid & 63, wid = tid >> 6;
    const int c = blockIdx.x % CC, bl = blockIdx.x / CC, b = b_start + bl;
    const float gam = gamma[0];
    const int4 IZ = make_int4(0, 0, 0, 0);
    const f32x4 FZ = {0.f, 0.f, 0.f, 0.f};
    const int pfirst = (gam == 0.f) ? 3 : 0;

    // zero ONLY pad rows of hb (rows 0,1 and 170..179); conv0 fills rows 2..169
    if (tid < 16) hbv[tid] = IZ;                       // bytes 0..255 (rows 0,1)
    if (tid >= 32 && tid < 112) hbv[1328 + tid] = IZ;  // bytes 21760..23039 (rows 170..179)
    if (tid < 176) {
        int l = tid - 2;
        xl[tid] = (l >= 0 && l < LL) ? x[((size_t)b * LL + l) * CC + c] : 0.f;
    }
    __syncthreads();   // xl + pad-zero visible

    // ---- conv0: fo = lane, l segment = wid*42 .. +42 (rolling window) ----
    {
        float wt0 = w0[lane*5], wt1 = w0[lane*5+1], wt2 = w0[lane*5+2],
              wt3 = w0[lane*5+3], wt4 = w0[lane*5+4];
        float bb = cb0[lane];
        const int l0 = wid * 42;
        float h0 = xl[l0], h1 = xl[l0+1], h2 = xl[l0+2], h3 = xl[l0+3];
        #pragma unroll 6
        for (int i = 0; i < 42; ++i) {
            float h4 = xl[l0 + i + 4];
            float a = bb + wt0*h0 + wt1*h1 + wt2*h2 + wt3*h3 + wt4*h4;
            int row = l0 + i + 2;
            *(_Float16*)(hb + row*128 + ((lane*2) ^ ((row&7)<<4))) = (_Float16)fmaxf(a, 0.f);
            h0 = h1; h1 = h2; h2 = h3; h3 = h4;
        }
    }
    __syncthreads();   // conv0 h visible

    const int fo = lane & 15;
    const int g8 = (lane >> 4) << 4;

    // ---- conv1..3 via MFMA: M=fo(4 mt), N=l(11 nt over 4 waves), K=fi (2 kk, 5 t) ----
    #pragma unroll 1
    for (int layer = 0; layer < 3; ++layer) {
        const float* bias = (layer == 0) ? cb1 : (layer == 1) ? cb2 : cb3;
        f32x4 acc[4][3];
        #pragma unroll
        for (int mt = 0; mt < 4; ++mt)
            #pragma unroll
            for (int i = 0; i < 3; ++i) acc[mt][i] = FZ;

        #pragma unroll
        for (int kk = 0; kk < 2; ++kk) {
            const _Float16* wb = wcb + layer*20480 + kk*10240 + lane*8;
            const int cb = kk*64 + g8;
            #pragma unroll
            for (int t = 0; t < 5; ++t) {
                // per-t A batch: 4 coalesced dwordx4 from L1-hot weights (16 VGPR live)
                half8 a0 = *(const half8*)(wb + t*2048 + 0*512);
                half8 a1 = *(const half8*)(wb + t*2048 + 1*512);
                half8 a2 = *(const half8*)(wb + t*2048 + 2*512);
                half8 a3 = *(const half8*)(wb + t*2048 + 3*512);
                #pragma unroll
                for (int i = 0; i < 3; ++i) {
                    const int nt = wid + 4*i;
                    if (nt < 11) {
                        int row = nt*16 + fo + t;
                        half8 bf = *(const half8*)(hb + row*128 + (cb ^ ((row&7)<<4)));
                        acc[0][i] = MFMA16(a0, bf, acc[0][i]);
                        acc[1][i] = MFMA16(a1, bf, acc[1][i]);
                        acc[2][i] = MFMA16(a2, bf, acc[2][i]);
                        acc[3][i] = MFMA16(a3, bf, acc[3][i]);
                    }
                }
            }
        }
        __syncthreads();   // all hb reads complete before in-place write

        // epilogue: bias + relu; layers 0,1 -> h in place; layer 2 -> pk repack (d-major k')
        if (layer < 2) {
            #pragma unroll
            for (int mt = 0; mt < 4; ++mt) {
                const int fo0 = mt*16 + ((lane>>4)<<2);
                const float bb0 = bias[fo0], bb1 = bias[fo0+1],
                            bb2 = bias[fo0+2], bb3 = bias[fo0+3];
                #pragma unroll
                for (int i = 0; i < 3; ++i) {
                    const int nt = wid + 4*i;
                    const int l  = nt*16 + fo;
                    if (nt < 11 && l < LL) {
                        int row = l + 2;
                        half4 hv;
                        hv.x = (_Float16)fmaxf(acc[mt][i].x + bb0, 0.f);
                        hv.y = (_Float16)fmaxf(acc[mt][i].y + bb1, 0.f);
                        hv.z = (_Float16)fmaxf(acc[mt][i].z + bb2, 0.f);
                        hv.w = (_Float16)fmaxf(acc[mt][i].w + bb3, 0.f);
                        *(half4*)(hb + row*128 + ((fo0*2) ^ ((row&7)<<4))) = hv;
                    }
                }
            }
        } else {
            #pragma unroll
            for (int mt = 0; mt < 4; ++mt) {
                const int fo0 = mt*16 + ((lane>>4)<<2);
                const float bb0 = bias[fo0], bb1 = bias[fo0+1],
                            bb2 = bias[fo0+2], bb3 = bias[fo0+3];
                #pragma unroll
                for (int i = 0; i < 3; ++i) {
                    const int nt = wid + 4*i;
                    const int l  = nt*16 + fo;
                    if (nt < 11 && l < LL) {
                        const int s = l / 3, d = l - s*3;
                        const int ssw = (s & 7) << 4;
                        half4 hv;
                        hv.x = (_Float16)fmaxf(acc[mt][i].x + bb0, 0.f);
                        hv.y = (_Float16)fmaxf(acc[mt][i].y + bb1, 0.f);
                        hv.z = (_Float16)fmaxf(acc[mt][i].z + bb2, 0.f);
                        hv.w = (_Float16)fmaxf(acc[mt][i].w + bb3, 0.f);
                        // k' = d*64 + f: one contiguous half4 at f=fo0..fo0+3
                        *(half4*)(hb + s*384 + ((d*128 + fo0*2) ^ ssw)) = hv;
                    }
                }
            }
        }
        __syncthreads();   // writes visible
    }

    // ---- projections: A = pwb[p] in registers, B = pk in hb; output staged via obuf ----
    const half8 HZ = {(_Float16)0,(_Float16)0,(_Float16)0,(_Float16)0,
                      (_Float16)0,(_Float16)0,(_Float16)0,(_Float16)0};
    #pragma unroll 1
    for (int p = pfirst; p < 4; ++p) {
        f32x4 pacc[4] = {FZ, FZ, FZ, FZ};
        const _Float16* ab = pwb + p*12288 + wid*512 + lane*8;
        #pragma unroll
        for (int kkp = 0; kkp < 6; ++kkp) {
            half8 af = *(const half8*)(ab + kkp*2048);
            const int cb = kkp*64 + g8;
            #pragma unroll
            for (int nt = 0; nt < 4; ++nt) {
                const int s = nt*16 + fo;
                half8 bf = HZ;
                if (s < SSTEP)
                    bf = *(const half8*)(hb + s*384 + (cb ^ ((s&7)<<4)));
                pacc[nt] = MFMA16(af, bf, pacc[nt]);
            }
        }
        // stage this p-slice into obuf [s][q] (swizzled rows)
        __syncthreads();   // prior copy-loop reads of obuf complete
        const int q0 = wid*16 + ((lane>>4)<<2);
        const bool relu = (p == 3 && gam == 0.f);
        #pragma unroll
        for (int nt = 0; nt < 4; ++nt) {
            const int s = nt*16 + fo;
            if (s >= SSTEP) continue;
            half4 o;
            if (relu) {
                o.x = (_Float16)fmaxf(pacc[nt].x, 0.f);
                o.y = (_Float16)fmaxf(pacc[nt].y, 0.f);
                o.z = (_Float16)fmaxf(pacc[nt].z, 0.f);
                o.w = (_Float16)fmaxf(pacc[nt].w, 0.f);
            } else {
                o.x = (_Float16)pacc[nt].x;
                o.y = (_Float16)pacc[nt].y;
                o.z = (_Float16)pacc[nt].z;
                o.w = (_Float16)pacc[nt].w;
            }
            *(half4*)(ob + s*128 + ((q0*2) ^ ((s&7)<<4))) = o;
        }
        __syncthreads();   // obuf complete
        // coalesced nontemporal write: 56 rows x 128B full segments
        for (int i = tid; i < 448; i += 256) {
            int s = i >> 3, j = i & 7;
            i32x4 v = *(const i32x4*)(ob + s*128 + ((j*16) ^ ((s&7)<<4)));
            _Float16* dst;
            if (relu) {
                const size_t bsO = (size_t)b * SSTEP + s;     // GLOBAL row
                dst = O + bsO*2304 + c*64 + j*8;
            } else {
                const size_t bsP = (size_t)bl * SSTEP + s;    // chunk-local row
                dst = P + (bsP*4 + p)*2304 + c*64 + j*8;
            }
            __builtin_nontemporal_store(v, (i32x4*)dst);
        }
    }
}

// ---------------- K2: attention (general gamma path only) ----------------
__global__ __launch_bounds__(256) void k2_attn(
    const _Float16* __restrict__ P,
    const float* __restrict__ gamma,
    _Float16* __restrict__ O)      // chunk-offset pointer
{
    const float gam = gamma[0];
    if (gam == 0.f) return;
    const int bs  = blockIdx.x;
    const int tid = threadIdx.x;
    __shared__ float pb[4][CC][FF];
    __shared__ float sc[CC][CC];

    const size_t base = (size_t)bs * 4 * 2304;
    for (int idx = tid; idx < 4 * 2304; idx += 256)
        ((float*)pb)[idx] = (float)P[base + idx];
    __syncthreads();

    for (int idx = tid; idx < CC * CC; idx += 256) {
        int i = idx / CC, jj = idx % CC;
        float a = 0.f;
        for (int qq = 0; qq < FF; ++qq) a += pb[0][i][qq] * pb[1][jj][qq];
        sc[i][jj] = a;
    }
    __syncthreads();
    if (tid < CC) {
        int jj = tid;
        float m = -1e30f;
        for (int i = 0; i < CC; ++i) m = fmaxf(m, sc[i][jj]);
        float ssum = 0.f;
        for (int i = 0; i < CC; ++i) ssum += expf(sc[i][jj] - m);
        float inv = 1.f / ssum;
        for (int i = 0; i < CC; ++i) sc[i][jj] = expf(sc[i][jj] - m) * inv;
    }
    __syncthreads();

    for (int idx = tid; idx < FF * CC; idx += 256) {
        int qq = idx / CC, jj = idx % CC;
        float a = 0.f;
        for (int i = 0; i < CC; ++i) a += pb[2][i][qq] * sc[i][jj];
        float o = gam * a + pb[3][jj][qq];
        O[(size_t)bs * 2304 + jj * 64 + qq] = (_Float16)fmaxf(o, 0.f);
    }
}

// ---------------- K3: FC via MFMA, BK=64 (8 MFMA per barrier-pair), single launch ----------------
__global__ __launch_bounds__(256) void k3_fc(
    const _Float16* __restrict__ O,     // [rows][2304]
    const _Float16* __restrict__ fcB,   // [256][2304]
    const float* __restrict__ fcb,
    float* __restrict__ out,            // [rows][256]
    int rows, int gm)
{
    const int bm = blockIdx.x % gm, bn = blockIdx.x / gm;
    const int r0 = bm * 64, c0 = bn * 64;
    const int tid = threadIdx.x, lane = tid & 63, wid = tid >> 6;
    __shared__ _Float16 As[64][72];   // 144B stride (16B aligned, ~2-way banks)
    __shared__ _Float16 Bs[64][72];

    const f32x4 FZ = {0.f, 0.f, 0.f, 0.f};
    f32x4 acc[4] = {FZ, FZ, FZ, FZ};
    const int rr = tid >> 2, k8 = (tid & 3) * 8;   // 4 threads per row, 2x int4 each
    const int4 IZ = make_int4(0, 0, 0, 0);
    const int fo = lane & 15, g = lane >> 4;

    for (int k0 = 0; k0 < 2304; k0 += 64) {
        __syncthreads();
        {
            const bool rok = (r0 + rr < rows);
            int4 a0 = rok ? *(const int4*)(O + (size_t)(r0 + rr) * 2304 + k0 + k8) : IZ;
            int4 a1 = rok ? *(const int4*)(O + (size_t)(r0 + rr) * 2304 + k0 + 32 + k8) : IZ;
            *(int4*)&As[rr][k8]      = a0;
            *(int4*)&As[rr][k8 + 32] = a1;
            *(int4*)&Bs[rr][k8]      = *(const int4*)(fcB + (size_t)(c0 + rr) * 2304 + k0 + k8);
            *(int4*)&Bs[rr][k8 + 32] = *(const int4*)(fcB + (size_t)(c0 + rr) * 2304 + k0 + 32 + k8);
        }
        __syncthreads();
        #pragma unroll
        for (int kk2 = 0; kk2 < 2; ++kk2) {
            const int ko = kk2*32 + g*8;
            half8 af = *(const half8*)&As[wid*16 + fo][ko];
            #pragma unroll
            for (int ct = 0; ct < 4; ++ct) {
                half8 bf = *(const half8*)&Bs[ct*16 + fo][ko];
                acc[ct] = MFMA16(af, bf, acc[ct]);
            }
        }
    }
    #pragma unroll
    for (int ct = 0; ct < 4; ++ct) {
        const int d = c0 + ct*16 + fo;
        const float bb = fcb[d];
        #pragma unroll
        for (int r = 0; r < 4; ++r) {
            const int row = r0 + wid*16 + g*4 + r;
            if (row < rows) out[(size_t)row * 256 + d] = fmaxf(acc[ct][r] + bb, 0.f);
        }
    }
}

extern "C" void kernel_launch(void* const* d_in, const int* in_sizes, int n_in,
                              void* d_out, int out_size, void* d_ws, size_t ws_size,
                              hipStream_t stream)
{
    const float* x     = (const float*)d_in[0];
    const float* w0    = (const float*)d_in[1];
    const float* b0    = (const float*)d_in[2];
    const float* w1    = (const float*)d_in[3];
    const float* b1    = (const float*)d_in[4];
    const float* w2    = (const float*)d_in[5];
    const float* b2    = (const float*)d_in[6];
    const float* w3    = (const float*)d_in[7];
    const float* b3    = (const float*)d_in[8];
    const float* wq    = (const float*)d_in[9];
    const float* wk    = (const float*)d_in[10];
    const float* wv    = (const float*)d_in[11];
    const float* wv1   = (const float*)d_in[12];
    const float* gamma = (const float*)d_in[13];
    const float* fcw   = (const float*)d_in[14];
    const float* fcb   = (const float*)d_in[15];
    float* out = (float*)d_out;

    // ws: weights (1.4MB) | O full [256*56][2304] f16 (66MB) | P chunk [Bc*56][4][2304] f16
    const size_t fixedB  = (size_t)(61440 + 49152 + 589824) * 2;          // 1,400,832
    const size_t O_FULL  = (size_t)BB * SSTEP * 2304 * 2;                 // 66,060,288
    const size_t perB_P  = (size_t)SSTEP * 4 * 2304 * 2;                  // 1,032,192
    int Bc = 256;
    while (Bc > 1 && fixedB + O_FULL + (size_t)Bc * perB_P > ws_size) Bc >>= 1;

    char* ws = (char*)d_ws;
    _Float16* wcb = (_Float16*)ws;
    _Float16* pwb = wcb + 61440;
    _Float16* fcB = pwb + 49152;
    _Float16* O   = (_Float16*)(ws + fixedB);
    _Float16* P   = O + (size_t)BB * SSTEP * 2304;

    const int prep_total = 61440 + 49152 + 589824;
    k0_prep<<<(prep_total + 255) / 256, 256, 0, stream>>>(w1, w2, w3, wq, wk, wv, wv1,
                                                          fcw, wcb, pwb, fcB);

    for (int bst = 0; bst < BB; bst += Bc) {
        int bcur = (bst + Bc <= BB) ? Bc : (BB - bst);
        k1_conv_proj<<<bcur * CC, 256, 0, stream>>>(x, w0, b0, b1, b2, b3,
                                                    wcb, pwb, gamma, P, O, bst);
        k2_attn<<<bcur * SSTEP, 256, 0, stream>>>(P, gamma,
                                                  O + (size_t)bst * SSTEP * 2304);
    }
    k3_fc<<<224 * 4, 256, 0, stream>>>(O, fcB, fcb, out, BB * SSTEP, 224);
}